// Round 1
// baseline (97.623 us; speedup 1.0000x reference)
//
#include <hip/hip_runtime.h>
#include <math.h>

// DRR via Siddon ray tracing. Geometry fixed: 256^3 volume, 256x256 detector.
// 8 threads cooperate on one ray, each traversing 1/8 of the [amin,amax] span.

#define NPLANE 256          // planes 0..256 per axis (257 planes)
constexpr int TPR = 8;      // threads per ray (power of 2, divides 64)

__device__ __forceinline__ float axis_alpha(int i, float sp, float src, float sdd) {
    return ((float)i * sp - src) / sdd;   // IEEE div, matches reference formula
}

__global__ __launch_bounds__(256) void drr_kernel(
    const float* __restrict__ vol,
    const float* __restrict__ spacing,
    const float* __restrict__ sdrp,
    const float* __restrict__ rot,
    const float* __restrict__ trans,
    float* __restrict__ out)
{
    int gid  = blockIdx.x * blockDim.x + threadIdx.x;
    int ray  = gid >> 3;      // TPR = 8
    int part = gid & 7;
    int ti   = ray >> 8;      // detector row (t / u direction)
    int si   = ray & 255;     // detector col (s / v direction)

    // --- rotation R = Rz(theta) @ Ry(phi) @ Rx(gamma), need columns 0,1,2 ---
    float theta = rot[0], phi = rot[1], gam = rot[2];
    float ct = cosf(theta), st = sinf(theta);
    float cp = cosf(phi),   sp_ = sinf(phi);
    float cg = cosf(gam),   sg = sinf(gam);

    float r0x = ct * cp,              r0y = st * cp,              r0z = -sp_;
    float ux  = ct * sp_ * sg - st * cg, uy = st * sp_ * sg + ct * cg, uz = cp * sg;
    float vx  = ct * sp_ * cg + st * sg, vy = st * sp_ * cg - ct * sg, vz = cp * cg;

    float sdr = sdrp[0];
    float tx = trans[0], ty = trans[1], tz = trans[2];

    // source and detector-plane center
    float sx = sdr * r0x + tx,  sy = sdr * r0y + ty,  sz = sdr * r0z + tz;
    float cxx = -sdr * r0x + tx, cxy = -sdr * r0y + ty, cxz = -sdr * r0z + tz;

    float tval = (float)(ti - 127) * 2.0f;   // (arange(-128,128)+1)*DELX
    float sval = (float)(si - 127) * 2.0f;   // (arange(-128,128)+1)*DELY

    float gx = tval * ux + sval * vx + cxx;
    float gy = tval * uy + sval * vy + cxy;
    float gz = tval * uz + sval * vz + cxz;

    float sdx = gx - sx + 1e-8f;
    float sdy = gy - sy + 1e-8f;
    float sdz = gz - sz + 1e-8f;

    float spx = spacing[0], spy = spacing[1], spz = spacing[2];

    // entry/exit parameters
    float a0x = (0.f - sx) / sdx, a1x = (256.f * spx - sx) / sdx;
    float a0y = (0.f - sy) / sdy, a1y = (256.f * spy - sy) / sdy;
    float a0z = (0.f - sz) / sdz, a1z = (256.f * spz - sz) / sdz;

    float amin = fmaxf(fmaxf(fminf(a0x, a1x), fminf(a0y, a1y)), fminf(a0z, a1z));
    float amax = fminf(fminf(fmaxf(a0x, a1x), fmaxf(a0y, a1y)), fmaxf(a0z, a1z));

    float acc = 0.f;

    if (amax > amin) {
        float range = amax - amin;
        // partition [amin,amax] into TPR slices; thread p owns segments whose
        // START crossing lies in [lo, hi). lo(p) is bit-identical to hi(p-1).
        float lo = fmaf(range, (float)part * 0.125f, amin);
        float hi = (part == TPR - 1) ? INFINITY
                                     : fmaf(range, (float)(part + 1) * 0.125f, amin);

        // per-axis: find first plane crossing with alpha >= lo
        int ix, iy, iz, dix, diy, diz;
        float nxx, nxy, nxz;

        #define SETUP(sp, src, sdd, I, DI, NXT)                                   \
        {                                                                         \
            float q = (src + lo * (sdd)) / (sp);                                  \
            if ((sdd) > 0.f) {                                                    \
                DI = 1;                                                           \
                float qc = ceilf(q);                                              \
                I = (qc < 0.f) ? 0 : ((qc > 256.f) ? 257 : (int)qc);              \
                while (I > 0   && axis_alpha(I - 1, sp, src, sdd) >= lo) --I;     \
                while (I <= NPLANE && axis_alpha(I, sp, src, sdd) < lo)  ++I;     \
                NXT = (I <= NPLANE) ? axis_alpha(I, sp, src, sdd) : INFINITY;     \
            } else {                                                              \
                DI = -1;                                                          \
                float qf = floorf(q);                                             \
                I = (qf > 256.f) ? NPLANE : ((qf < 0.f) ? -1 : (int)qf);          \
                while (I < NPLANE && axis_alpha(I + 1, sp, src, sdd) >= lo) ++I;  \
                while (I >= 0  && axis_alpha(I, sp, src, sdd) < lo) --I;          \
                NXT = (I >= 0) ? axis_alpha(I, sp, src, sdd) : INFINITY;          \
            }                                                                     \
        }

        SETUP(spx, sx, sdx, ix, dix, nxx)
        SETUP(spy, sy, sdy, iy, diy, nxy)
        SETUP(spz, sz, sdz, iz, diz, nxz)
        #undef SETUP

        float cur = fminf(fminf(nxx, nxy), nxz);   // first crossing >= lo

        float ispx = 1.0f / spx, ispy = 1.0f / spy, ispz = 1.0f / spz;

        while (cur < hi && cur < amax) {
            // advance every axis whose pending crossing == cur
            if (nxx == cur) { ix += dix; nxx = (ix >= 0 && ix <= NPLANE) ? axis_alpha(ix, spx, sx, sdx) : INFINITY; }
            if (nxy == cur) { iy += diy; nxy = (iy >= 0 && iy <= NPLANE) ? axis_alpha(iy, spy, sy, sdy) : INFINITY; }
            if (nxz == cur) { iz += diz; nxz = (iz >= 0 && iz <= NPLANE) ? axis_alpha(iz, spz, sz, sdz) : INFINITY; }
            float nxt  = fminf(fminf(nxx, nxy), nxz);
            float e    = fminf(nxt, amax);
            float step = e - cur;
            if (step > 0.f) {
                float amid = 0.5f * (cur + e);
                float pxv = fmaf(amid, sdx, sx) * ispx;
                float pyv = fmaf(amid, sdy, sy) * ispy;
                float pzv = fmaf(amid, sdz, sz) * ispz;
                int jx = (int)pxv; jx = jx < 0 ? 0 : (jx > 255 ? 255 : jx);
                int jy = (int)pyv; jy = jy < 0 ? 0 : (jy > 255 ? 255 : jy);
                int jz = (int)pzv; jz = jz < 0 ? 0 : (jz > 255 ? 255 : jz);
                acc = fmaf(vol[(jx << 16) | (jy << 8) | jz], step, acc);
            }
            cur = nxt;
        }
    }

    // combine the 8 partial integrals (lanes of one ray are contiguous)
    for (int off = TPR / 2; off > 0; off >>= 1)
        acc += __shfl_down(acc, off, TPR);

    if (part == 0) {
        float rl = sqrtf(sdx * sdx + sdy * sdy + sdz * sdz);
        out[ray] = acc * rl;
    }
}

extern "C" void kernel_launch(void* const* d_in, const int* in_sizes, int n_in,
                              void* d_out, int out_size, void* d_ws, size_t ws_size,
                              hipStream_t stream) {
    const float* vol     = (const float*)d_in[0];
    const float* spacing = (const float*)d_in[1];
    const float* sdr     = (const float*)d_in[2];
    const float* rot     = (const float*)d_in[3];
    const float* trans   = (const float*)d_in[4];
    float* out = (float*)d_out;

    int total = 256 * 256 * TPR;   // 524288 threads
    drr_kernel<<<total / 256, 256, 0, stream>>>(vol, spacing, sdr, rot, trans, out);
}